// Round 1
// baseline (7591.619 us; speedup 1.0000x reference)
//
#include <hip/hip_runtime.h>
#include <hip/hip_bf16.h>

// Problem dims
#define VOCAB 50257
#define EMBED 512
#define HIDDEN 1024
#define TSEQ 2048
#define NPAD 50304            // VOCAB padded to multiple of 128
#define LOGITS_SIZE ((size_t)TSEQ * VOCAB)   // 102,926,336

// Workspace layout
#define OFF_XP   ((size_t)0)                          // fp32 [2048][1024]  = 8 MB
#define OFF_HS   ((size_t)(TSEQ * HIDDEN * 4))        // bf16 [2048][1024]  = 4 MB
#define OFF_H    (OFF_HS + (size_t)TSEQ * HIDDEN * 2) // fp32 2x[1024] ping-pong = 8 KB
#define OFF_BAR  (OFF_H + 8192)                       // barrier counter
#define OFF_WB   (OFF_BAR + 256)                      // bf16 [50304][1024] = 103 MB
#define WS_NEED_FULL (OFF_WB + (size_t)NPAD * HIDDEN * 2)

typedef short bf16x8 __attribute__((ext_vector_type(8)));
typedef float f32x4  __attribute__((ext_vector_type(4)));
typedef short short8 __attribute__((ext_vector_type(8)));

static __device__ __forceinline__ unsigned short f2bf(float f) {
    unsigned u = __float_as_uint(f);
    unsigned r = (u + 0x7fffu + ((u >> 16) & 1u)) >> 16;
    return (unsigned short)r;
}

// ---------------------------------------------------------------------------
// Kernel 1: xp[t][j] = sum_k emb[x[t]][k] * W_xh[j][k]   (fp32, 64x64 tiles)
// ---------------------------------------------------------------------------
__global__ __launch_bounds__(256, 2) void emb_xp_kernel(
    const int* __restrict__ x, const float* __restrict__ emb,
    const float* __restrict__ Wxh, float* __restrict__ xp)
{
    __shared__ float As[64][68];   // +4 pad: stride 272B (16B-aligned, conflict-free)
    __shared__ float Bs[64][68];
    __shared__ int   xs[64];
    const int tid = threadIdx.x;
    const int t0 = blockIdx.y * 64, j0 = blockIdx.x * 64;
    if (tid < 64) xs[tid] = x[t0 + tid];
    __syncthreads();
    const int ty = tid >> 4, tx = tid & 15;
    float acc[4][4] = {};
    for (int kc = 0; kc < EMBED; kc += 64) {
        __syncthreads();
#pragma unroll
        for (int i = 0; i < 4; ++i) {
            int s = i * 256 + tid;            // 1024 float4 slots
            int r = s >> 4, c4 = s & 15;
            *(float4*)&As[r][c4 * 4] = *(const float4*)&emb[(size_t)xs[r] * EMBED + kc + c4 * 4];
            *(float4*)&Bs[r][c4 * 4] = *(const float4*)&Wxh[(size_t)(j0 + r) * EMBED + kc + c4 * 4];
        }
        __syncthreads();
        for (int kk = 0; kk < 64; ++kk) {
            float a[4], b[4];
#pragma unroll
            for (int u = 0; u < 4; ++u) a[u] = As[ty + 16 * u][kk];
#pragma unroll
            for (int v = 0; v < 4; ++v) b[v] = Bs[tx + 16 * v][kk];
#pragma unroll
            for (int u = 0; u < 4; ++u)
#pragma unroll
                for (int v = 0; v < 4; ++v) acc[u][v] += a[u] * b[v];
        }
    }
#pragma unroll
    for (int u = 0; u < 4; ++u)
#pragma unroll
        for (int v = 0; v < 4; ++v)
            xp[(size_t)(t0 + ty + 16 * u) * HIDDEN + j0 + tx + 16 * v] = acc[u][v];
}

// ---------------------------------------------------------------------------
// Kernel 2: W_out fp32 -> bf16, padded to NPAD rows (pad rows = 0)
// ---------------------------------------------------------------------------
__global__ void conv_wout_kernel(const float* __restrict__ W, unsigned short* __restrict__ Wb)
{
    size_t i = (size_t)blockIdx.x * blockDim.x + threadIdx.x;  // float4 index
    size_t idx = i * 4;
    if (idx >= (size_t)NPAD * HIDDEN) return;
    size_t row = idx >> 10;
    float4 v = make_float4(0.f, 0.f, 0.f, 0.f);
    if (row < VOCAB) v = *(const float4*)&W[idx];
    ushort4 o = make_ushort4(f2bf(v.x), f2bf(v.y), f2bf(v.z), f2bf(v.w));
    *(ushort4*)&Wb[idx] = o;
}

// ---------------------------------------------------------------------------
// Kernel 3: sequential recurrence. 32 persistent WGs x 512 threads.
// WG w owns j in [w*32, w*32+32); 16 threads per j; thread holds 64 W_hh
// elements in registers (interleaved: i = ii*64 + k16*4 + c).
// Double-buffered h + agent-scope release/acquire spin barrier per step.
// ---------------------------------------------------------------------------
#define RNN_WGS 32
__global__ __launch_bounds__(512, 2) void rnn_recur_kernel(
    const float* __restrict__ xp, const float* __restrict__ Whh,
    const float* __restrict__ bhh, float* g_h /* 2x1024 ping-pong */,
    unsigned short* __restrict__ hs_bf16, float* __restrict__ h_final,
    int* bar)
{
    const int tid = threadIdx.x;
    const int j = blockIdx.x * 32 + (tid >> 4);
    const int k16 = tid & 15;

    float4 w4[16];
#pragma unroll
    for (int ii = 0; ii < 16; ++ii)
        w4[ii] = *(const float4*)&Whh[(size_t)j * HIDDEN + ii * 64 + k16 * 4];
    const float bj = bhh[j];

    __shared__ float hsm[HIDDEN];

    for (int t = 0; t < TSEQ; ++t) {
        const float* hin = g_h + ((t & 1) << 10);
        float* hout      = g_h + (((t + 1) & 1) << 10);
        if (tid < 256) *(float4*)&hsm[tid * 4] = *(const float4*)&hin[tid * 4];
        __syncthreads();

        float sum = 0.f;
#pragma unroll
        for (int ii = 0; ii < 16; ++ii) {
            float4 h4 = *(const float4*)&hsm[ii * 64 + k16 * 4];
            sum += w4[ii].x * h4.x + w4[ii].y * h4.y + w4[ii].z * h4.z + w4[ii].w * h4.w;
        }
        sum += __shfl_xor(sum, 1);
        sum += __shfl_xor(sum, 2);
        sum += __shfl_xor(sum, 4);
        sum += __shfl_xor(sum, 8);

        float val = tanhf(sum + bj + xp[(size_t)t * HIDDEN + j]);
        if (k16 == 0) {
            hout[j] = val;
            hs_bf16[(size_t)t * HIDDEN + j] = f2bf(val);
            if (t == TSEQ - 1) h_final[j] = val;
        }
        __syncthreads();   // compiler drains vmcnt per wave before s_barrier
        if (tid == 0) {
            __hip_atomic_fetch_add(bar, 1, __ATOMIC_RELEASE, __HIP_MEMORY_SCOPE_AGENT);
            const int target = RNN_WGS * (t + 1);
            while (__hip_atomic_load(bar, __ATOMIC_ACQUIRE, __HIP_MEMORY_SCOPE_AGENT) < target)
                __builtin_amdgcn_s_sleep(1);
        }
        __syncthreads();
    }
}

// ---------------------------------------------------------------------------
// Kernel 4: logits = hs @ W_out.T + b_out.  bf16 MFMA, 128x128 tile,
// 4 waves (2x2), each wave 64x64 via 4x4 of 16x16x32 MFMAs. Register staging.
// ---------------------------------------------------------------------------
template <bool PRE>
__global__ __launch_bounds__(256, 2) void out_gemm_kernel(
    const unsigned short* __restrict__ hs,      // bf16 [2048][1024]
    const unsigned short* __restrict__ Wb,      // bf16 [NPAD][1024]   (PRE)
    const float* __restrict__ Wf,               // fp32 [VOCAB][1024]  (!PRE)
    const float* __restrict__ b_out,
    float* __restrict__ out)
{
    __shared__ short As[128 * 32];
    __shared__ short Bs[128 * 32];
    const int tid = threadIdx.x;
    const int wid = tid >> 6, lane = tid & 63;
    const int wm = wid >> 1, wn = wid & 1;
    const int l15 = lane & 15, quad = lane >> 4;
    const int m0 = blockIdx.y * 128, n0 = blockIdx.x * 128;

    f32x4 acc[4][4];
#pragma unroll
    for (int a = 0; a < 4; ++a)
#pragma unroll
        for (int b = 0; b < 4; ++b) acc[a][b] = (f32x4){0.f, 0.f, 0.f, 0.f};

    for (int k0 = 0; k0 < HIDDEN; k0 += 32) {
        __syncthreads();
        // A tile: [128][32] bf16, rows K-contiguous
#pragma unroll
        for (int i = 0; i < 2; ++i) {
            int ss = i * 256 + tid;
            int r = ss >> 2, c = ss & 3;
            short8 av = *(const short8*)(hs + (size_t)(m0 + r) * HIDDEN + k0 + c * 8);
            *(short8*)&As[r * 32 + c * 8] = av;
        }
        if (PRE) {
#pragma unroll
            for (int i = 0; i < 2; ++i) {
                int ss = i * 256 + tid;
                int r = ss >> 2, c = ss & 3;
                short8 bv = *(const short8*)(Wb + (size_t)(n0 + r) * HIDDEN + k0 + c * 8);
                *(short8*)&Bs[r * 32 + c * 8] = bv;
            }
        } else {
#pragma unroll
            for (int i = 0; i < 4; ++i) {
                int ss = i * 256 + tid;
                int r = ss >> 3, c4 = ss & 7;
                float4 v = make_float4(0.f, 0.f, 0.f, 0.f);
                if (n0 + r < VOCAB) v = *(const float4*)&Wf[(size_t)(n0 + r) * HIDDEN + k0 + c4 * 4];
                ushort4 u = make_ushort4(f2bf(v.x), f2bf(v.y), f2bf(v.z), f2bf(v.w));
                *(ushort4*)&Bs[r * 32 + c4 * 4] = u;
            }
        }
        __syncthreads();

        bf16x8 af[4], bfr[4];
#pragma unroll
        for (int mi = 0; mi < 4; ++mi)
            af[mi] = *(const bf16x8*)&As[(wm * 64 + mi * 16 + l15) * 32 + quad * 8];
#pragma unroll
        for (int ni = 0; ni < 4; ++ni)
            bfr[ni] = *(const bf16x8*)&Bs[(wn * 64 + ni * 16 + l15) * 32 + quad * 8];
#pragma unroll
        for (int mi = 0; mi < 4; ++mi)
#pragma unroll
            for (int ni = 0; ni < 4; ++ni)
                acc[mi][ni] = __builtin_amdgcn_mfma_f32_16x16x32_bf16(af[mi], bfr[ni], acc[mi][ni], 0, 0, 0);
    }

    // Epilogue: C/D layout col = lane&15, row = quad*4 + reg
#pragma unroll
    for (int ni = 0; ni < 4; ++ni) {
        int n = n0 + wn * 64 + ni * 16 + l15;
        bool ok = n < VOCAB;
        float bias = ok ? b_out[n] : 0.f;
#pragma unroll
        for (int mi = 0; mi < 4; ++mi) {
            int mbase = m0 + wm * 64 + mi * 16 + quad * 4;
#pragma unroll
            for (int r = 0; r < 4; ++r) {
                if (ok) out[(size_t)(mbase + r) * VOCAB + n] = acc[mi][ni][r] + bias;
            }
        }
    }
}

// ---------------------------------------------------------------------------
extern "C" void kernel_launch(void* const* d_in, const int* in_sizes, int n_in,
                              void* d_out, int out_size, void* d_ws, size_t ws_size,
                              hipStream_t stream)
{
    const int*   x     = (const int*)d_in[0];
    const float* emb   = (const float*)d_in[1];
    const float* W_xh  = (const float*)d_in[2];
    const float* W_hh  = (const float*)d_in[3];
    const float* b_hh  = (const float*)d_in[4];
    const float* W_out = (const float*)d_in[5];
    const float* b_out = (const float*)d_in[6];
    float* out = (float*)d_out;
    char* ws = (char*)d_ws;

    float*          xp  = (float*)(ws + OFF_XP);
    unsigned short* hsb = (unsigned short*)(ws + OFF_HS);
    float*          g_h = (float*)(ws + OFF_H);
    int*            bar = (int*)(ws + OFF_BAR);
    unsigned short* Wb  = (unsigned short*)(ws + OFF_WB);

    // zero h ping-pong buffers (h0 = 0) and barrier counter (ws is poisoned 0xAA)
    hipMemsetAsync(ws + OFF_H, 0, 8192 + 256, stream);

    emb_xp_kernel<<<dim3(HIDDEN / 64, TSEQ / 64), 256, 0, stream>>>(x, emb, W_xh, xp);

    const bool pre = ws_size >= WS_NEED_FULL;
    if (pre)
        conv_wout_kernel<<<(NPAD * HIDDEN / 4 + 255) / 256, 256, 0, stream>>>(W_out, Wb);

    rnn_recur_kernel<<<RNN_WGS, 512, 0, stream>>>(xp, W_hh, b_hh, g_h, hsb,
                                                  out + LOGITS_SIZE, bar);

    if (pre)
        out_gemm_kernel<true><<<dim3(NPAD / 128, TSEQ / 128), 256, 0, stream>>>(
            hsb, Wb, nullptr, b_out, out);
    else
        out_gemm_kernel<false><<<dim3(NPAD / 128, TSEQ / 128), 256, 0, stream>>>(
            hsb, nullptr, W_out, b_out, out);
}